// Round 1
// baseline (1572.272 us; speedup 1.0000x reference)
//
#include <hip/hip_runtime.h>
#include <math.h>

#define FIN 128
#define HDIM 64

__device__ __forceinline__ float wsum(float v) {
#pragma unroll
    for (int m = 1; m < 64; m <<= 1) v += __shfl_xor(v, m, 64);
    return v;
}
__device__ __forceinline__ float wmax(float v) {
#pragma unroll
    for (int m = 1; m < 64; m <<= 1) v = fmaxf(v, __shfl_xor(v, m, 64));
    return v;
}

// h = x @ W1 + b1 ; rn = 1/max(||h_row||, 1e-12). One wave per row, lane = output feature.
__global__ __launch_bounds__(256) void gemm_norm_k(
    const float* __restrict__ x, const float* __restrict__ W,
    const float* __restrict__ b, float* __restrict__ h,
    float* __restrict__ rn, int n)
{
    __shared__ float sW[FIN * HDIM];   // 32 KB
    __shared__ float sb[HDIM];
    for (int i = threadIdx.x; i < FIN * HDIM; i += 256) sW[i] = W[i];
    if (threadIdx.x < HDIM) sb[threadIdx.x] = b[threadIdx.x];
    __syncthreads();
    const int lane = threadIdx.x & 63;
    const int gw = (int)((blockIdx.x * 256 + threadIdx.x) >> 6);
    const int nw = (int)((gridDim.x * 256) >> 6);
    for (int row = gw; row < n; row += nw) {
        const float* xr = x + (size_t)row * FIN;
        float x0 = xr[lane];
        float x1 = xr[lane + 64];
        float acc = sb[lane];
#pragma unroll
        for (int k = 0; k < 64; ++k)
            acc = fmaf(__shfl(x0, k, 64), sW[k * HDIM + lane], acc);
#pragma unroll
        for (int k = 0; k < 64; ++k)
            acc = fmaf(__shfl(x1, k, 64), sW[(k + 64) * HDIM + lane], acc);
        h[(size_t)row * HDIM + lane] = acc;
        float ss = wsum(acc * acc);
        if (lane == 0) rn[row] = 1.0f / fmaxf(sqrtf(ss), 1e-12f);
    }
}

// rn = 1/max(||h_row||, eps) for prop2's input
__global__ __launch_bounds__(256) void norm_k(
    const float* __restrict__ h, float* __restrict__ rn, int n)
{
    const int lane = threadIdx.x & 63;
    const int gw = (int)((blockIdx.x * 256 + threadIdx.x) >> 6);
    const int nw = (int)((gridDim.x * 256) >> 6);
    for (int row = gw; row < n; row += nw) {
        float v = h[(size_t)row * HDIM + lane];
        float ss = wsum(v * v);
        if (lane == 0) rn[row] = 1.0f / fmaxf(sqrtf(ss), 1e-12f);
    }
}

// Pass 1 over edges: e = exp(beta*cos(src,dst) - |beta|); ssum[dst] += e
// Self loops appended: e in [E, Etot) -> src = dst = e - E.
// Softmax shift-invariance => uniform shift |beta| replaces segment_max exactly.
__global__ __launch_bounds__(256) void edge_p1(
    const float* __restrict__ h, const float* __restrict__ rn,
    const int* __restrict__ ei, const float* __restrict__ beta_ptr,
    float* __restrict__ ebuf, float* __restrict__ ssum, int E, int Etot)
{
    const int lane = threadIdx.x & 63;
    const int gw = (int)((blockIdx.x * 256 + threadIdx.x) >> 6);
    const int nw = (int)((gridDim.x * 256) >> 6);
    const float beta = beta_ptr ? beta_ptr[0] : 1.0f;
    const float shift = fabsf(beta);
    for (int e = gw; e < Etot; e += nw) {
        int s, d;
        if (e < E) { s = ei[e]; d = ei[E + e]; }
        else       { s = e - E; d = s; }
        float p = h[(size_t)s * HDIM + lane] * h[(size_t)d * HDIM + lane];
        p = wsum(p);
        if (lane == 0) {
            float l = beta * p * rn[s] * rn[d];
            float ev = __expf(l - shift);
            ebuf[e] = ev;
            atomicAdd(&ssum[d], ev);
        }
    }
}

// Pass 2 over edges: out[dst] += (ebuf[e]/ssum[dst]) * h[src], lane-wise atomics
__global__ __launch_bounds__(256) void edge_p2(
    const float* __restrict__ h, const float* __restrict__ ssum,
    const int* __restrict__ ei, const float* __restrict__ ebuf,
    float* __restrict__ out, int E, int Etot)
{
    const int lane = threadIdx.x & 63;
    const int gw = (int)((blockIdx.x * 256 + threadIdx.x) >> 6);
    const int nw = (int)((gridDim.x * 256) >> 6);
    for (int e = gw; e < Etot; e += nw) {
        int s, d;
        if (e < E) { s = ei[e]; d = ei[E + e]; }
        else       { s = e - E; d = s; }
        float alpha = ebuf[e] / ssum[d];
        atomicAdd(&out[(size_t)d * HDIM + lane],
                  alpha * h[(size_t)s * HDIM + lane]);
    }
}

__global__ __launch_bounds__(256) void logsoftmax_k(
    const float* __restrict__ h, float* __restrict__ out, int n)
{
    const int lane = threadIdx.x & 63;
    const int gw = (int)((blockIdx.x * 256 + threadIdx.x) >> 6);
    const int nw = (int)((gridDim.x * 256) >> 6);
    for (int row = gw; row < n; row += nw) {
        float v = h[(size_t)row * HDIM + lane];
        float m = wmax(v);
        float e = __expf(v - m);
        float sum = wsum(e);
        out[(size_t)row * HDIM + lane] = v - m - __logf(sum);
    }
}

extern "C" void kernel_launch(void* const* d_in, const int* in_sizes, int n_in,
                              void* d_out, int out_size, void* d_ws, size_t ws_size,
                              hipStream_t stream)
{
    const float* x     = (const float*)d_in[0];
    const int*   ei    = (const int*)d_in[1];   // [2, E] int32
    const float* W1    = (const float*)d_in[2];
    const float* b1    = (const float*)d_in[3];
    const float* beta2 = (const float*)d_in[4];
    float* out = (float*)d_out;

    const int N    = in_sizes[0] / FIN;
    const int E    = in_sizes[1] / 2;
    const int Etot = E + N;

    // workspace layout (floats): h1[N*64] h2[N*64] ebuf[Etot] ssum[N] rn[N]
    float* h1   = (float*)d_ws;
    float* h2   = h1 + (size_t)N * HDIM;
    float* ebuf = h2 + (size_t)N * HDIM;
    float* ssum = ebuf + (size_t)Etot;
    float* rn   = ssum + (size_t)N;

    const dim3 blk(256);
    const int rowBlocks  = 1024;
    const int edgeBlocks = 2048;

    // h1 = x@W1+b1, rn = row inv-norms
    gemm_norm_k<<<2048, blk, 0, stream>>>(x, W1, b1, h1, rn, N);

    // ---- prop 1 (beta = 1.0) ----
    hipMemsetAsync(ssum, 0, (size_t)N * sizeof(float), stream);
    edge_p1<<<edgeBlocks, blk, 0, stream>>>(h1, rn, ei, nullptr, ebuf, ssum, E, Etot);
    hipMemsetAsync(h2, 0, (size_t)N * HDIM * sizeof(float), stream);
    edge_p2<<<edgeBlocks, blk, 0, stream>>>(h1, ssum, ei, ebuf, h2, E, Etot);

    // ---- prop 2 (beta = beta2[0]) ----
    norm_k<<<rowBlocks, blk, 0, stream>>>(h2, rn, N);
    hipMemsetAsync(ssum, 0, (size_t)N * sizeof(float), stream);
    edge_p1<<<edgeBlocks, blk, 0, stream>>>(h2, rn, ei, beta2, ebuf, ssum, E, Etot);
    hipMemsetAsync(h1, 0, (size_t)N * HDIM * sizeof(float), stream);
    edge_p2<<<edgeBlocks, blk, 0, stream>>>(h2, ssum, ei, ebuf, h1, E, Etot);

    // log_softmax
    logsoftmax_k<<<rowBlocks, blk, 0, stream>>>(h1, out, N);
}

// Round 2
// 808.387 us; speedup vs baseline: 1.9449x; 1.9449x over previous
//
#include <hip/hip_runtime.h>
#include <math.h>

#define FIN 128
#define HDIM 64

__device__ __forceinline__ float wsum(float v) {
#pragma unroll
    for (int m = 1; m < 64; m <<= 1) v += __shfl_xor(v, m, 64);
    return v;
}
__device__ __forceinline__ float wmax(float v) {
#pragma unroll
    for (int m = 1; m < 64; m <<= 1) v = fmaxf(v, __shfl_xor(v, m, 64));
    return v;
}

// ---------------- CSR build ----------------

// counts[d]++ for every edge (self loops appended: e in [E,Etot) -> s=d=e-E)
__global__ __launch_bounds__(256) void hist_k(
    const int* __restrict__ ei, int* __restrict__ counts, int E, int Etot)
{
    int i = blockIdx.x * 256 + threadIdx.x;
    int stride = gridDim.x * 256;
    for (int e = i; e < Etot; e += stride) {
        int d = (e < E) ? ei[E + e] : (e - E);
        atomicAdd(&counts[d], 1);
    }
}

// Single-block hierarchical exclusive scan of counts[n] -> offsets[n+1].
// Also rewrites counts[i] = exclusive prefix (reused as the scatter cursor).
__global__ __launch_bounds__(1024) void scan_k(
    int* __restrict__ counts, int* __restrict__ offsets, int n)
{
    __shared__ int wpart[16];
    const int lane = threadIdx.x & 63;
    const int wid  = threadIdx.x >> 6;
    int carry = 0;
    for (int base = 0; base < n; base += 4096) {
        int idx = base + (int)threadIdx.x * 4;
        int v0 = (idx + 0 < n) ? counts[idx + 0] : 0;
        int v1 = (idx + 1 < n) ? counts[idx + 1] : 0;
        int v2 = (idx + 2 < n) ? counts[idx + 2] : 0;
        int v3 = (idx + 3 < n) ? counts[idx + 3] : 0;
        int tsum = v0 + v1 + v2 + v3;
        // inclusive scan of per-thread totals across the wave
        int s = tsum;
#pragma unroll
        for (int off = 1; off < 64; off <<= 1) {
            int u = __shfl_up(s, off, 64);
            if (lane >= off) s += u;
        }
        if (lane == 63) wpart[wid] = s;
        __syncthreads();
        if (wid == 0 && lane < 16) {
            int w = wpart[lane];
#pragma unroll
            for (int off = 1; off < 16; off <<= 1) {
                int u = __shfl_up(w, off, 64);
                if (lane >= off) w += u;
            }
            wpart[lane] = w;          // inclusive scan of wave totals
        }
        __syncthreads();
        int wexcl = (wid == 0) ? 0 : wpart[wid - 1];
        int total = wpart[15];
        int tex = carry + wexcl + (s - tsum);   // exclusive base for this thread
        int e0 = tex, e1 = tex + v0, e2 = e1 + v1, e3 = e2 + v2;
        if (idx + 0 < n) { offsets[idx + 0] = e0; counts[idx + 0] = e0; }
        if (idx + 1 < n) { offsets[idx + 1] = e1; counts[idx + 1] = e1; }
        if (idx + 2 < n) { offsets[idx + 2] = e2; counts[idx + 2] = e2; }
        if (idx + 3 < n) { offsets[idx + 3] = e3; counts[idx + 3] = e3; }
        carry += total;
        __syncthreads();              // wpart reused next chunk
    }
    if (threadIdx.x == 0) offsets[n] = carry;
}

// csr[cursor[d]++] = src  (order within a segment is irrelevant)
__global__ __launch_bounds__(256) void scatter_k(
    const int* __restrict__ ei, int* __restrict__ cursor,
    int* __restrict__ csr, int E, int Etot)
{
    int i = blockIdx.x * 256 + threadIdx.x;
    int stride = gridDim.x * 256;
    for (int e = i; e < Etot; e += stride) {
        int s, d;
        if (e < E) { s = ei[e]; d = ei[E + e]; }
        else       { s = e - E; d = s; }
        int pos = atomicAdd(&cursor[d], 1);
        csr[pos] = s;
    }
}

// ---------------- dense compute ----------------

// hn = normalize(x@W1+b1) rows; nrm = row L2 norm. One wave per row.
__global__ __launch_bounds__(256) void gemm_norm_k(
    const float* __restrict__ x, const float* __restrict__ W,
    const float* __restrict__ b, float* __restrict__ hn,
    float* __restrict__ nrm, int n)
{
    __shared__ float sW[FIN * HDIM];   // 32 KB
    __shared__ float sb[HDIM];
    for (int i = threadIdx.x; i < FIN * HDIM; i += 256) sW[i] = W[i];
    if (threadIdx.x < HDIM) sb[threadIdx.x] = b[threadIdx.x];
    __syncthreads();
    const int lane = threadIdx.x & 63;
    const int gw = (int)((blockIdx.x * 256 + threadIdx.x) >> 6);
    const int nw = (int)((gridDim.x * 256) >> 6);
    for (int row = gw; row < n; row += nw) {
        const float* xr = x + (size_t)row * FIN;
        float x0 = xr[lane];
        float x1 = xr[lane + 64];
        float acc = sb[lane];
#pragma unroll
        for (int k = 0; k < 64; ++k)
            acc = fmaf(__shfl(x0, k, 64), sW[k * HDIM + lane], acc);
#pragma unroll
        for (int k = 0; k < 64; ++k)
            acc = fmaf(__shfl(x1, k, 64), sW[(k + 64) * HDIM + lane], acc);
        float ss = wsum(acc * acc);
        float norm = sqrtf(ss);
        float rinv = 1.0f / fmaxf(norm, 1e-12f);
        hn[(size_t)row * HDIM + lane] = acc * rinv;
        if (lane == 0) nrm[row] = norm;
    }
}

// AGNN propagation, one wave per destination node, CSR gather, no atomics.
// logit = beta * dot(hn[s], hn[d]); softmax with uniform shift |beta| (exact).
// out row o = sum_e exp(l-|b|)*nrm[s]*hn[s] / sum_e exp(l-|b|).
// If lsm_out != null: write log_softmax(o) there (final layer).
// Else: write normalized o to hn_out and its norm to nrm_out.
__global__ __launch_bounds__(256) void prop_k(
    const float* __restrict__ hn, const float* __restrict__ nrm,
    const int* __restrict__ offsets, const int* __restrict__ csr,
    const float* __restrict__ beta_ptr,
    float* __restrict__ hn_out, float* __restrict__ nrm_out,
    float* __restrict__ lsm_out, int n)
{
    const int lane = threadIdx.x & 63;
    const int gw = (int)((blockIdx.x * 256 + threadIdx.x) >> 6);
    const int nw = (int)((gridDim.x * 256) >> 6);
    const float beta = beta_ptr ? beta_ptr[0] : 1.0f;
    const float shift = fabsf(beta);
    for (int d = gw; d < n; d += nw) {
        const float hd = hn[(size_t)d * HDIM + lane];
        const int i0 = offsets[d], i1 = offsets[d + 1];
        float acc = 0.f, ssum = 0.f;
        int i = i0;
        for (; i + 1 < i1; i += 2) {           // unroll x2: pipeline gathers
            int s0 = csr[i], s1 = csr[i + 1];
            float va = hn[(size_t)s0 * HDIM + lane];
            float vb = hn[(size_t)s1 * HDIM + lane];
            float na = nrm[s0], nb = nrm[s1];
            float pa = va * hd, pb = vb * hd;
#pragma unroll
            for (int m = 1; m < 64; m <<= 1) {
                pa += __shfl_xor(pa, m, 64);
                pb += __shfl_xor(pb, m, 64);
            }
            float ea = __expf(beta * pa - shift);
            float eb = __expf(beta * pb - shift);
            acc = fmaf(ea * na, va, acc);
            acc = fmaf(eb * nb, vb, acc);
            ssum += ea + eb;
        }
        if (i < i1) {
            int s0 = csr[i];
            float va = hn[(size_t)s0 * HDIM + lane];
            float pa = wsum(va * hd);
            float ea = __expf(beta * pa - shift);
            acc = fmaf(ea * nrm[s0], va, acc);
            ssum += ea;
        }
        float o = acc / ssum;                  // self loop guarantees ssum>0
        if (lsm_out) {
            float m = wmax(o);
            float e = __expf(o - m);
            float sum = wsum(e);
            lsm_out[(size_t)d * HDIM + lane] = o - m - __logf(sum);
        } else {
            float ss = wsum(o * o);
            float norm = sqrtf(ss);
            float rinv = 1.0f / fmaxf(norm, 1e-12f);
            hn_out[(size_t)d * HDIM + lane] = o * rinv;
            if (lane == 0) nrm_out[d] = norm;
        }
    }
}

extern "C" void kernel_launch(void* const* d_in, const int* in_sizes, int n_in,
                              void* d_out, int out_size, void* d_ws, size_t ws_size,
                              hipStream_t stream)
{
    const float* x     = (const float*)d_in[0];
    const int*   ei    = (const int*)d_in[1];   // [2, E] int32 (harness-converted)
    const float* W1    = (const float*)d_in[2];
    const float* b1    = (const float*)d_in[3];
    const float* beta2 = (const float*)d_in[4];
    float* out = (float*)d_out;

    const int N    = in_sizes[0] / FIN;
    const int E    = in_sizes[1] / 2;
    const int Etot = E + N;

    // ws layout (4B elems): hn1[N*64] hn2[N*64] nrm1[N] nrm2[N]
    //                       counts[N] (becomes cursor) offsets[N+1] csr[Etot]
    float* hn1     = (float*)d_ws;
    float* hn2     = hn1 + (size_t)N * HDIM;
    float* nrm1    = hn2 + (size_t)N * HDIM;
    float* nrm2    = nrm1 + N;
    int*   counts  = (int*)(nrm2 + N);
    int*   offsets = counts + N;
    int*   csr     = offsets + (N + 1);

    const dim3 blk(256);
    const int edgeBlocks = 4096;
    const int rowBlocks  = 4096;

    // ---- CSR build (topology shared by both props) ----
    hipMemsetAsync(counts, 0, (size_t)N * sizeof(int), stream);
    hist_k<<<edgeBlocks, blk, 0, stream>>>(ei, counts, E, Etot);
    scan_k<<<1, 1024, 0, stream>>>(counts, offsets, N);
    scatter_k<<<edgeBlocks, blk, 0, stream>>>(ei, counts, csr, E, Etot);

    // ---- h = x@W1+b1, normalized ----
    gemm_norm_k<<<2048, blk, 0, stream>>>(x, W1, b1, hn1, nrm1, N);

    // ---- prop 1 (beta = 1.0) ----
    prop_k<<<rowBlocks, blk, 0, stream>>>(hn1, nrm1, offsets, csr, nullptr,
                                          hn2, nrm2, nullptr, N);
    // ---- prop 2 (beta = beta2[0]) + fused log_softmax ----
    prop_k<<<rowBlocks, blk, 0, stream>>>(hn2, nrm2, offsets, csr, beta2,
                                          nullptr, nullptr, out, N);
}

// Round 3
// 549.451 us; speedup vs baseline: 2.8615x; 1.4713x over previous
//
#include <hip/hip_runtime.h>
#include <math.h>

#define FIN 128
#define HDIM 64

typedef __attribute__((ext_vector_type(8))) short short8_t;  // 8 bf16 (4 VGPRs)
typedef __attribute__((ext_vector_type(4))) float f32x4;

__device__ __forceinline__ void split_bf16(float f, unsigned short& hi, unsigned short& lo) {
    unsigned b = __builtin_bit_cast(unsigned, f);
    hi = (unsigned short)(b >> 16);
    float fh = __builtin_bit_cast(float, b & 0xFFFF0000u);
    float fl = f - fh;
    lo = (unsigned short)(__builtin_bit_cast(unsigned, fl) >> 16);
}

// ---------------- CSR build ----------------

__global__ __launch_bounds__(256) void hist_k(
    const int* __restrict__ ei, int* __restrict__ counts, int E, int Etot)
{
    int i = blockIdx.x * 256 + threadIdx.x;
    int stride = gridDim.x * 256;
    for (int e = i; e < Etot; e += stride) {
        int d = (e < E) ? ei[E + e] : (e - E);
        atomicAdd(&counts[d], 1);
    }
}

// Single-block hierarchical exclusive scan: counts[n] -> offsets[n+1]; counts := cursor
__global__ __launch_bounds__(1024) void scan_k(
    int* __restrict__ counts, int* __restrict__ offsets, int n)
{
    __shared__ int wpart[16];
    const int lane = threadIdx.x & 63;
    const int wid  = threadIdx.x >> 6;
    int carry = 0;
    for (int base = 0; base < n; base += 4096) {
        int idx = base + (int)threadIdx.x * 4;
        int v0 = (idx + 0 < n) ? counts[idx + 0] : 0;
        int v1 = (idx + 1 < n) ? counts[idx + 1] : 0;
        int v2 = (idx + 2 < n) ? counts[idx + 2] : 0;
        int v3 = (idx + 3 < n) ? counts[idx + 3] : 0;
        int tsum = v0 + v1 + v2 + v3;
        int s = tsum;
#pragma unroll
        for (int off = 1; off < 64; off <<= 1) {
            int u = __shfl_up(s, off, 64);
            if (lane >= off) s += u;
        }
        if (lane == 63) wpart[wid] = s;
        __syncthreads();
        if (wid == 0 && lane < 16) {
            int w = wpart[lane];
#pragma unroll
            for (int off = 1; off < 16; off <<= 1) {
                int u = __shfl_up(w, off, 64);
                if (lane >= off) w += u;
            }
            wpart[lane] = w;
        }
        __syncthreads();
        int wexcl = (wid == 0) ? 0 : wpart[wid - 1];
        int total = wpart[15];
        int tex = carry + wexcl + (s - tsum);
        int e0 = tex, e1 = tex + v0, e2 = e1 + v1, e3 = e2 + v2;
        if (idx + 0 < n) { offsets[idx + 0] = e0; counts[idx + 0] = e0; }
        if (idx + 1 < n) { offsets[idx + 1] = e1; counts[idx + 1] = e1; }
        if (idx + 2 < n) { offsets[idx + 2] = e2; counts[idx + 2] = e2; }
        if (idx + 3 < n) { offsets[idx + 3] = e3; counts[idx + 3] = e3; }
        carry += total;
        __syncthreads();
    }
    if (threadIdx.x == 0) offsets[n] = carry;
}

__global__ __launch_bounds__(256) void scatter_k(
    const int* __restrict__ ei, int* __restrict__ cursor,
    int* __restrict__ csr, int E, int Etot)
{
    int i = blockIdx.x * 256 + threadIdx.x;
    int stride = gridDim.x * 256;
    for (int e = i; e < Etot; e += stride) {
        int s, d;
        if (e < E) { s = ei[e]; d = ei[E + e]; }
        else       { s = e - E; d = s; }
        int pos = atomicAdd(&cursor[d], 1);
        csr[pos] = s;
    }
}

// ---------------- GEMM via MFMA (fp32 emulated with bf16 hi/lo split) ----------------
// h = x@W + b; hn = normalize(h); nrm = ||h||. Wave computes 16 rows x 64 cols.
// A frag (16x32): lane holds row=lane&15, k=(lane>>4)*8+j. B frag: col=lane&15, same k.
// C/D: col=lane&15, row=(lane>>4)*4+reg  [verified layout, learn_hip m89/m91].
__global__ __launch_bounds__(256) void gemm_mfma_k(
    const float* __restrict__ x, const float* __restrict__ W,
    const float* __restrict__ b, float* __restrict__ hn,
    float* __restrict__ nrm, int n)
{
    __shared__ uint4 sB[2][4][4][64];   // [hi/lo][kc][nt][lane] = 32 KB
    for (int idx = threadIdx.x; idx < 2048; idx += 256) {
        int lanei = idx & 63;
        int f = idx >> 6;              // hl*16 + kc*4 + nt
        int nt = f & 3, kc = (f >> 2) & 3, hl = f >> 4;
        int col = nt * 16 + (lanei & 15);
        int kb  = kc * 32 + (lanei >> 4) * 8;
        unsigned u[4];
#pragma unroll
        for (int jj = 0; jj < 4; ++jj) {
            unsigned short h0, l0, h1, l1;
            split_bf16(W[(size_t)(kb + 2 * jj)     * HDIM + col], h0, l0);
            split_bf16(W[(size_t)(kb + 2 * jj + 1) * HDIM + col], h1, l1);
            u[jj] = hl ? ((unsigned)l0 | ((unsigned)l1 << 16))
                       : ((unsigned)h0 | ((unsigned)h1 << 16));
        }
        uint4 q; q.x = u[0]; q.y = u[1]; q.z = u[2]; q.w = u[3];
        sB[hl][kc][nt][lanei] = q;
    }
    __syncthreads();

    const int lane = threadIdx.x & 63;
    const int l15 = lane & 15, l4 = lane >> 4;
    const int gw = (int)((blockIdx.x * 256 + threadIdx.x) >> 6);
    const int nw = (int)((gridDim.x * 256) >> 6);
    const int ntiles = (n + 15) >> 4;

    const float bc0 = b[l15], bc1 = b[16 + l15], bc2 = b[32 + l15], bc3 = b[48 + l15];

    for (int tile = gw; tile < ntiles; tile += nw) {
        const int rowbase = tile << 4;
        int arow = rowbase + l15; if (arow >= n) arow = n - 1;
        const float* xp = x + (size_t)arow * FIN + l4 * 8;

        f32x4 acc0 = {bc0, bc0, bc0, bc0};
        f32x4 acc1 = {bc1, bc1, bc1, bc1};
        f32x4 acc2 = {bc2, bc2, bc2, bc2};
        f32x4 acc3 = {bc3, bc3, bc3, bc3};

#pragma unroll
        for (int kc = 0; kc < 4; ++kc) {
            float4 xa = *(const float4*)(xp + kc * 32);
            float4 xb = *(const float4*)(xp + kc * 32 + 4);
            float v[8] = {xa.x, xa.y, xa.z, xa.w, xb.x, xb.y, xb.z, xb.w};
            short8_t ah, al;
#pragma unroll
            for (int j = 0; j < 8; ++j) {
                unsigned bb = __builtin_bit_cast(unsigned, v[j]);
                ah[j] = (short)(bb >> 16);
                float fl = v[j] - __builtin_bit_cast(float, bb & 0xFFFF0000u);
                al[j] = (short)(__builtin_bit_cast(unsigned, fl) >> 16);
            }
#pragma unroll
            for (int nt = 0; nt < 4; ++nt) {
                short8_t bh = __builtin_bit_cast(short8_t, sB[0][kc][nt][lane]);
                short8_t bl = __builtin_bit_cast(short8_t, sB[1][kc][nt][lane]);
                f32x4* pacc = (nt == 0) ? &acc0 : (nt == 1) ? &acc1 : (nt == 2) ? &acc2 : &acc3;
                *pacc = __builtin_amdgcn_mfma_f32_16x16x32_bf16(ah, bh, *pacc, 0, 0, 0);
                *pacc = __builtin_amdgcn_mfma_f32_16x16x32_bf16(al, bh, *pacc, 0, 0, 0);
                *pacc = __builtin_amdgcn_mfma_f32_16x16x32_bf16(ah, bl, *pacc, 0, 0, 0);
            }
        }

        // row norms: reg r -> row rowbase + 4*l4 + r, cols spread over l15 (x4 nt)
        float ss0 = acc0.x*acc0.x + acc1.x*acc1.x + acc2.x*acc2.x + acc3.x*acc3.x;
        float ss1 = acc0.y*acc0.y + acc1.y*acc1.y + acc2.y*acc2.y + acc3.y*acc3.y;
        float ss2 = acc0.z*acc0.z + acc1.z*acc1.z + acc2.z*acc2.z + acc3.z*acc3.z;
        float ss3 = acc0.w*acc0.w + acc1.w*acc1.w + acc2.w*acc2.w + acc3.w*acc3.w;
#pragma unroll
        for (int m = 1; m < 16; m <<= 1) {
            ss0 += __shfl_xor(ss0, m, 64);
            ss1 += __shfl_xor(ss1, m, 64);
            ss2 += __shfl_xor(ss2, m, 64);
            ss3 += __shfl_xor(ss3, m, 64);
        }
        float n0 = sqrtf(ss0), n1 = sqrtf(ss1), n2 = sqrtf(ss2), n3 = sqrtf(ss3);
        float r0 = 1.0f / fmaxf(n0, 1e-12f), r1 = 1.0f / fmaxf(n1, 1e-12f);
        float r2 = 1.0f / fmaxf(n2, 1e-12f), r3 = 1.0f / fmaxf(n3, 1e-12f);
        const int rowb = rowbase + l4 * 4;
        if (l15 == 0) {
            if (rowb + 0 < n) nrm[rowb + 0] = n0;
            if (rowb + 1 < n) nrm[rowb + 1] = n1;
            if (rowb + 2 < n) nrm[rowb + 2] = n2;
            if (rowb + 3 < n) nrm[rowb + 3] = n3;
        }
#pragma unroll
        for (int nt = 0; nt < 4; ++nt) {
            f32x4 a = (nt == 0) ? acc0 : (nt == 1) ? acc1 : (nt == 2) ? acc2 : acc3;
            const int col = nt * 16 + l15;
            if (rowb + 0 < n) hn[(size_t)(rowb + 0) * HDIM + col] = a.x * r0;
            if (rowb + 1 < n) hn[(size_t)(rowb + 1) * HDIM + col] = a.y * r1;
            if (rowb + 2 < n) hn[(size_t)(rowb + 2) * HDIM + col] = a.z * r2;
            if (rowb + 3 < n) hn[(size_t)(rowb + 3) * HDIM + col] = a.w * r3;
        }
    }
}

// ---------------- AGNN propagation: wave per dst, 4 edges/iter via 16-lane subgroups ----
__global__ __launch_bounds__(256) void prop_k(
    const float* __restrict__ hn, const float* __restrict__ nrm,
    const int* __restrict__ offsets, const int* __restrict__ csr,
    const float* __restrict__ beta_ptr,
    float* __restrict__ hn_out, float* __restrict__ nrm_out,
    float* __restrict__ lsm_out, int n)
{
    const int lane = threadIdx.x & 63;
    const int sg = lane >> 4;        // subgroup 0..3 (one edge each)
    const int sl = lane & 15;        // 4 floats per lane -> 64 elems per subgroup
    const int gw = (int)((blockIdx.x * 256 + threadIdx.x) >> 6);
    const int nw = (int)((gridDim.x * 256) >> 6);
    const float beta = beta_ptr ? beta_ptr[0] : 1.0f;
    const float shift = fabsf(beta);

    for (int d = gw; d < n; d += nw) {
        const float4 hd = *(const float4*)(hn + (size_t)d * HDIM + sl * 4);
        const int i0 = offsets[d], i1 = offsets[d + 1];
        const int iters = (i1 - i0 + 3) >> 2;
        float ax = 0.f, ay = 0.f, az = 0.f, aw = 0.f, ssum = 0.f;
        for (int t = 0; t < iters; ++t) {
            const int e = i0 + t * 4 + sg;
            const bool valid = e < i1;
            const int s = valid ? csr[e] : d;
            const float4 va = *(const float4*)(hn + (size_t)s * HDIM + sl * 4);
            const float na = nrm[s];
            float p = va.x * hd.x + va.y * hd.y + va.z * hd.z + va.w * hd.w;
            p += __shfl_xor(p, 1, 64);
            p += __shfl_xor(p, 2, 64);
            p += __shfl_xor(p, 4, 64);
            p += __shfl_xor(p, 8, 64);
            const float ev = valid ? __expf(beta * p - shift) : 0.f;
            const float w = ev * na;
            ax = fmaf(w, va.x, ax); ay = fmaf(w, va.y, ay);
            az = fmaf(w, va.z, az); aw = fmaf(w, va.w, aw);
            ssum += ev;
        }
        // reduce across the 4 subgroups
#pragma unroll
        for (int m = 16; m < 64; m <<= 1) {
            ax += __shfl_xor(ax, m, 64); ay += __shfl_xor(ay, m, 64);
            az += __shfl_xor(az, m, 64); aw += __shfl_xor(aw, m, 64);
            ssum += __shfl_xor(ssum, m, 64);
        }
        const float rs = 1.0f / ssum;          // self loop => ssum > 0
        float ox = ax * rs, oy = ay * rs, oz = az * rs, ow = aw * rs;

        if (lsm_out) {
            float mx = fmaxf(fmaxf(ox, oy), fmaxf(oz, ow));
#pragma unroll
            for (int m = 1; m < 16; m <<= 1) mx = fmaxf(mx, __shfl_xor(mx, m, 64));
            float ex = __expf(ox - mx), ey = __expf(oy - mx);
            float ez = __expf(oz - mx), ew = __expf(ow - mx);
            float es = ex + ey + ez + ew;
#pragma unroll
            for (int m = 1; m < 16; m <<= 1) es += __shfl_xor(es, m, 64);
            float ls = __logf(es);
            if (sg == 0)
                *(float4*)(lsm_out + (size_t)d * HDIM + sl * 4) =
                    make_float4(ox - mx - ls, oy - mx - ls, oz - mx - ls, ow - mx - ls);
        } else {
            float ss = ox * ox + oy * oy + oz * oz + ow * ow;
#pragma unroll
            for (int m = 1; m < 16; m <<= 1) ss += __shfl_xor(ss, m, 64);
            float norm = sqrtf(ss);
            float rinv = 1.0f / fmaxf(norm, 1e-12f);
            if (sg == 0) {
                *(float4*)(hn_out + (size_t)d * HDIM + sl * 4) =
                    make_float4(ox * rinv, oy * rinv, oz * rinv, ow * rinv);
                if (sl == 0) nrm_out[d] = norm;
            }
        }
    }
}

extern "C" void kernel_launch(void* const* d_in, const int* in_sizes, int n_in,
                              void* d_out, int out_size, void* d_ws, size_t ws_size,
                              hipStream_t stream)
{
    const float* x     = (const float*)d_in[0];
    const int*   ei    = (const int*)d_in[1];   // [2, E] int32
    const float* W1    = (const float*)d_in[2];
    const float* b1    = (const float*)d_in[3];
    const float* beta2 = (const float*)d_in[4];
    float* out = (float*)d_out;

    const int N    = in_sizes[0] / FIN;
    const int E    = in_sizes[1] / 2;
    const int Etot = E + N;

    // ws layout (4B elems): hn1[N*64] hn2[N*64] nrm1[N] nrm2[N]
    //                       counts[N] offsets[N+1] csr[Etot]
    float* hn1     = (float*)d_ws;
    float* hn2     = hn1 + (size_t)N * HDIM;
    float* nrm1    = hn2 + (size_t)N * HDIM;
    float* nrm2    = nrm1 + N;
    int*   counts  = (int*)(nrm2 + N);
    int*   offsets = counts + N;
    int*   csr     = offsets + (N + 1);

    const dim3 blk(256);

    // ---- CSR build (topology shared by both props) ----
    hipMemsetAsync(counts, 0, (size_t)N * sizeof(int), stream);
    hist_k<<<2048, blk, 0, stream>>>(ei, counts, E, Etot);
    scan_k<<<1, 1024, 0, stream>>>(counts, offsets, N);
    scatter_k<<<2048, blk, 0, stream>>>(ei, counts, csr, E, Etot);

    // ---- h = x@W1+b1 (MFMA), normalized ----
    const int ntiles = (N + 15) >> 4;
    gemm_mfma_k<<<(ntiles + 3) / 4, blk, 0, stream>>>(x, W1, b1, hn1, nrm1, N);

    // ---- prop 1 (beta = 1.0) ----
    prop_k<<<4096, blk, 0, stream>>>(hn1, nrm1, offsets, csr, nullptr,
                                     hn2, nrm2, nullptr, N);
    // ---- prop 2 (beta = beta2[0]) + fused log_softmax ----
    prop_k<<<4096, blk, 0, stream>>>(hn2, nrm2, offsets, csr, beta2,
                                     nullptr, nullptr, out, N);
}

// Round 4
// 362.245 us; speedup vs baseline: 4.3404x; 1.5168x over previous
//
#include <hip/hip_runtime.h>
#include <math.h>

#define FIN 128
#define HDIM 64

// CSR-build (counting sort) geometry. Assumes N <= 131072 (src fits 17 bits,
// coarse buckets <= 64). Problem instance: N=100000, E=1.6M.
#define EB 8192            // edges per block in p1/p2
#define B2SHIFT 11
#define B2 (1 << B2SHIFT)  // 2048 dst per coarse bucket
#define SRCBITS 17
#define SRCMASK ((1u << SRCBITS) - 1u)

typedef __attribute__((ext_vector_type(8))) short short8_t;  // 8 bf16 (4 VGPRs)
typedef __attribute__((ext_vector_type(4))) float f32x4;

__device__ __forceinline__ void split_bf16(float f, unsigned short& hi, unsigned short& lo) {
    unsigned b = __builtin_bit_cast(unsigned, f);
    hi = (unsigned short)(b >> 16);
    float fh = __builtin_bit_cast(float, b & 0xFFFF0000u);
    float fl = f - fh;
    lo = (unsigned short)(__builtin_bit_cast(unsigned, fl) >> 16);
}

// ---------------- CSR build: deterministic two-level counting sort ----------------

// Per-block LDS histogram over coarse buckets -> ph[b][blk] (plain writes)
__global__ __launch_bounds__(256) void p1_hist(
    const int* __restrict__ ei, int* __restrict__ ph,
    int E, int Etot, int NB, int nblk)
{
    __shared__ int h[64];
    if (threadIdx.x < 64) h[threadIdx.x] = 0;
    __syncthreads();
    const int base = blockIdx.x * EB;
    const int end = min(base + EB, Etot);
    for (int e = base + (int)threadIdx.x; e < end; e += 256) {
        int d = (e < E) ? ei[E + e] : (e - E);
        atomicAdd(&h[d >> B2SHIFT], 1);
    }
    __syncthreads();
    if ((int)threadIdx.x < NB) ph[threadIdx.x * nblk + blockIdx.x] = h[threadIdx.x];
}

// Single small block: per-bucket exclusive scan over blocks (ph in-place),
// bucket totals -> exclusive bucket bases bbase[NB+1]; offsets[N] = Etot.
__global__ __launch_bounds__(256) void p1_scan(
    int* __restrict__ ph, int* __restrict__ bbase, int* __restrict__ offsets,
    int NB, int nblk, int N)
{
    __shared__ int btot[64];
    const int lane = threadIdx.x & 63, w = threadIdx.x >> 6;
    for (int b = w; b < NB; b += 4) {
        int carry = 0;
        for (int c = 0; c < nblk; c += 64) {
            int i = c + lane;
            int v = (i < nblk) ? ph[b * nblk + i] : 0;
            int s = v;
#pragma unroll
            for (int off = 1; off < 64; off <<= 1) {
                int u = __shfl_up(s, off, 64);
                if (lane >= off) s += u;
            }
            if (i < nblk) ph[b * nblk + i] = carry + s - v;   // exclusive within bucket
            carry += __shfl(s, 63, 64);
        }
        if (lane == 0) btot[b] = carry;
    }
    __syncthreads();
    if (w == 0) {
        int v = (lane < NB) ? btot[lane] : 0;
        int s = v;
#pragma unroll
        for (int off = 1; off < 64; off <<= 1) {
            int u = __shfl_up(s, off, 64);
            if (lane >= off) s += u;
        }
        if (lane < NB) bbase[lane] = s - v;
        if (lane == NB - 1) { bbase[NB] = s; offsets[N] = s; }  // s == Etot
    }
}

// Scatter edges into coarse-bucket chunks (deterministic per-block placement).
// pairs[pos] = (dst_local << 17) | src. Block's chunk per bucket is contiguous.
__global__ __launch_bounds__(256) void p2_scatter(
    const int* __restrict__ ei, const int* __restrict__ ph,
    const int* __restrict__ bbase, unsigned* __restrict__ pairs,
    int E, int Etot, int NB, int nblk)
{
    __shared__ int cur[64];
    if ((int)threadIdx.x < NB)
        cur[threadIdx.x] = bbase[threadIdx.x] + ph[threadIdx.x * nblk + blockIdx.x];
    __syncthreads();
    const int base = blockIdx.x * EB;
    const int end = min(base + EB, Etot);
    for (int e = base + (int)threadIdx.x; e < end; e += 256) {
        int s, d;
        if (e < E) { s = ei[e]; d = ei[E + e]; }
        else       { s = e - E; d = s; }
        int pos = atomicAdd(&cur[d >> B2SHIFT], 1);     // LDS atomic
        pairs[pos] = ((unsigned)(d & (B2 - 1)) << SRCBITS) | (unsigned)s;
    }
}

// One block per coarse bucket: LDS 2048-bin hist + scan -> offsets, then
// in-bucket scatter into contiguous (L2-resident) csr region.
__global__ __launch_bounds__(1024) void p3_csr(
    const unsigned* __restrict__ pairs, const int* __restrict__ bbase,
    int* __restrict__ offsets, int* __restrict__ csr, int N)
{
    __shared__ int hist[B2];
    __shared__ int wp[16];
    const int b = blockIdx.x;
    const int p0 = bbase[b], p1 = bbase[b + 1];
    const int dbase = b << B2SHIFT;
    const int lane = threadIdx.x & 63, w = threadIdx.x >> 6;
    hist[threadIdx.x] = 0; hist[threadIdx.x + 1024] = 0;
    __syncthreads();
    for (int i = p0 + (int)threadIdx.x; i < p1; i += 1024)
        atomicAdd(&hist[pairs[i] >> SRCBITS], 1);
    __syncthreads();
    // scan 2048 bins, thread t owns bins 2t, 2t+1
    const int v0 = hist[2 * threadIdx.x], v1 = hist[2 * threadIdx.x + 1];
    const int t = v0 + v1;
    int s = t;
#pragma unroll
    for (int off = 1; off < 64; off <<= 1) {
        int u = __shfl_up(s, off, 64);
        if (lane >= off) s += u;
    }
    if (lane == 63) wp[w] = s;
    __syncthreads();
    if (w == 0 && lane < 16) {
        int xx = wp[lane];
#pragma unroll
        for (int off = 1; off < 16; off <<= 1) {
            int u = __shfl_up(xx, off, 64);
            if (lane >= off) xx += u;
        }
        wp[lane] = xx;
    }
    __syncthreads();
    const int tex = ((w == 0) ? 0 : wp[w - 1]) + (s - t);
    const int e0 = tex, e1 = tex + v0;
    const int d0 = dbase + 2 * (int)threadIdx.x, d1 = d0 + 1;
    if (d0 < N) offsets[d0] = p0 + e0;
    if (d1 < N) offsets[d1] = p0 + e1;
    __syncthreads();
    hist[2 * threadIdx.x] = e0; hist[2 * threadIdx.x + 1] = e1;   // bucket-local cursors
    __syncthreads();
    for (int i = p0 + (int)threadIdx.x; i < p1; i += 1024) {
        unsigned pk = pairs[i];
        int pos = p0 + atomicAdd(&hist[pk >> SRCBITS], 1);
        csr[pos] = (int)(pk & SRCMASK);
    }
}

// ---------------- GEMM via MFMA (fp32 emulated with bf16 hi/lo split) ----------------
__global__ __launch_bounds__(256) void gemm_mfma_k(
    const float* __restrict__ x, const float* __restrict__ W,
    const float* __restrict__ b, float* __restrict__ hn,
    float* __restrict__ nrm, int n)
{
    __shared__ uint4 sB[2][4][4][64];   // [hi/lo][kc][nt][lane] = 32 KB
    for (int idx = threadIdx.x; idx < 2048; idx += 256) {
        int lanei = idx & 63;
        int f = idx >> 6;              // hl*16 + kc*4 + nt
        int nt = f & 3, kc = (f >> 2) & 3, hl = f >> 4;
        int col = nt * 16 + (lanei & 15);
        int kb  = kc * 32 + (lanei >> 4) * 8;
        unsigned u[4];
#pragma unroll
        for (int jj = 0; jj < 4; ++jj) {
            unsigned short h0, l0, h1, l1;
            split_bf16(W[(size_t)(kb + 2 * jj)     * HDIM + col], h0, l0);
            split_bf16(W[(size_t)(kb + 2 * jj + 1) * HDIM + col], h1, l1);
            u[jj] = hl ? ((unsigned)l0 | ((unsigned)l1 << 16))
                       : ((unsigned)h0 | ((unsigned)h1 << 16));
        }
        uint4 q; q.x = u[0]; q.y = u[1]; q.z = u[2]; q.w = u[3];
        sB[hl][kc][nt][lanei] = q;
    }
    __syncthreads();

    const int lane = threadIdx.x & 63;
    const int l15 = lane & 15, l4 = lane >> 4;
    const int gw = (int)((blockIdx.x * 256 + threadIdx.x) >> 6);
    const int nw = (int)((gridDim.x * 256) >> 6);
    const int ntiles = (n + 15) >> 4;

    const float bc0 = b[l15], bc1 = b[16 + l15], bc2 = b[32 + l15], bc3 = b[48 + l15];

    for (int tile = gw; tile < ntiles; tile += nw) {
        const int rowbase = tile << 4;
        int arow = rowbase + l15; if (arow >= n) arow = n - 1;
        const float* xp = x + (size_t)arow * FIN + l4 * 8;

        f32x4 acc0 = {bc0, bc0, bc0, bc0};
        f32x4 acc1 = {bc1, bc1, bc1, bc1};
        f32x4 acc2 = {bc2, bc2, bc2, bc2};
        f32x4 acc3 = {bc3, bc3, bc3, bc3};

#pragma unroll
        for (int kc = 0; kc < 4; ++kc) {
            float4 xa = *(const float4*)(xp + kc * 32);
            float4 xb = *(const float4*)(xp + kc * 32 + 4);
            float v[8] = {xa.x, xa.y, xa.z, xa.w, xb.x, xb.y, xb.z, xb.w};
            short8_t ah, al;
#pragma unroll
            for (int j = 0; j < 8; ++j) {
                unsigned bb = __builtin_bit_cast(unsigned, v[j]);
                ah[j] = (short)(bb >> 16);
                float fl = v[j] - __builtin_bit_cast(float, bb & 0xFFFF0000u);
                al[j] = (short)(__builtin_bit_cast(unsigned, fl) >> 16);
            }
#pragma unroll
            for (int nt = 0; nt < 4; ++nt) {
                short8_t bh = __builtin_bit_cast(short8_t, sB[0][kc][nt][lane]);
                short8_t bl = __builtin_bit_cast(short8_t, sB[1][kc][nt][lane]);
                f32x4* pacc = (nt == 0) ? &acc0 : (nt == 1) ? &acc1 : (nt == 2) ? &acc2 : &acc3;
                *pacc = __builtin_amdgcn_mfma_f32_16x16x32_bf16(ah, bh, *pacc, 0, 0, 0);
                *pacc = __builtin_amdgcn_mfma_f32_16x16x32_bf16(al, bh, *pacc, 0, 0, 0);
                *pacc = __builtin_amdgcn_mfma_f32_16x16x32_bf16(ah, bl, *pacc, 0, 0, 0);
            }
        }

        float ss0 = acc0.x*acc0.x + acc1.x*acc1.x + acc2.x*acc2.x + acc3.x*acc3.x;
        float ss1 = acc0.y*acc0.y + acc1.y*acc1.y + acc2.y*acc2.y + acc3.y*acc3.y;
        float ss2 = acc0.z*acc0.z + acc1.z*acc1.z + acc2.z*acc2.z + acc3.z*acc3.z;
        float ss3 = acc0.w*acc0.w + acc1.w*acc1.w + acc2.w*acc2.w + acc3.w*acc3.w;
#pragma unroll
        for (int m = 1; m < 16; m <<= 1) {
            ss0 += __shfl_xor(ss0, m, 64);
            ss1 += __shfl_xor(ss1, m, 64);
            ss2 += __shfl_xor(ss2, m, 64);
            ss3 += __shfl_xor(ss3, m, 64);
        }
        float n0 = sqrtf(ss0), n1 = sqrtf(ss1), n2 = sqrtf(ss2), n3 = sqrtf(ss3);
        float r0 = 1.0f / fmaxf(n0, 1e-12f), r1 = 1.0f / fmaxf(n1, 1e-12f);
        float r2 = 1.0f / fmaxf(n2, 1e-12f), r3 = 1.0f / fmaxf(n3, 1e-12f);
        const int rowb = rowbase + l4 * 4;
        if (l15 == 0) {
            if (rowb + 0 < n) nrm[rowb + 0] = n0;
            if (rowb + 1 < n) nrm[rowb + 1] = n1;
            if (rowb + 2 < n) nrm[rowb + 2] = n2;
            if (rowb + 3 < n) nrm[rowb + 3] = n3;
        }
#pragma unroll
        for (int nt = 0; nt < 4; ++nt) {
            f32x4 a = (nt == 0) ? acc0 : (nt == 1) ? acc1 : (nt == 2) ? acc2 : acc3;
            const int col = nt * 16 + l15;
            if (rowb + 0 < n) hn[(size_t)(rowb + 0) * HDIM + col] = a.x * r0;
            if (rowb + 1 < n) hn[(size_t)(rowb + 1) * HDIM + col] = a.y * r1;
            if (rowb + 2 < n) hn[(size_t)(rowb + 2) * HDIM + col] = a.z * r2;
            if (rowb + 3 < n) hn[(size_t)(rowb + 3) * HDIM + col] = a.w * r3;
        }
    }
}

// ---------------- AGNN propagation: wave per dst, 4 edges/iter via 16-lane subgroups ----
__global__ __launch_bounds__(256) void prop_k(
    const float* __restrict__ hn, const float* __restrict__ nrm,
    const int* __restrict__ offsets, const int* __restrict__ csr,
    const float* __restrict__ beta_ptr,
    float* __restrict__ hn_out, float* __restrict__ nrm_out,
    float* __restrict__ lsm_out, int n)
{
    const int lane = threadIdx.x & 63;
    const int sg = lane >> 4;
    const int sl = lane & 15;
    const int gw = (int)((blockIdx.x * 256 + threadIdx.x) >> 6);
    const int nw = (int)((gridDim.x * 256) >> 6);
    const float beta = beta_ptr ? beta_ptr[0] : 1.0f;
    const float shift = fabsf(beta);

    for (int d = gw; d < n; d += nw) {
        const float4 hd = *(const float4*)(hn + (size_t)d * HDIM + sl * 4);
        const int i0 = offsets[d], i1 = offsets[d + 1];
        const int iters = (i1 - i0 + 3) >> 2;
        float ax = 0.f, ay = 0.f, az = 0.f, aw = 0.f, ssum = 0.f;
        for (int t = 0; t < iters; ++t) {
            const int e = i0 + t * 4 + sg;
            const bool valid = e < i1;
            const int s = valid ? csr[e] : d;
            const float4 va = *(const float4*)(hn + (size_t)s * HDIM + sl * 4);
            const float na = nrm[s];
            float p = va.x * hd.x + va.y * hd.y + va.z * hd.z + va.w * hd.w;
            p += __shfl_xor(p, 1, 64);
            p += __shfl_xor(p, 2, 64);
            p += __shfl_xor(p, 4, 64);
            p += __shfl_xor(p, 8, 64);
            const float ev = valid ? __expf(beta * p - shift) : 0.f;
            const float w = ev * na;
            ax = fmaf(w, va.x, ax); ay = fmaf(w, va.y, ay);
            az = fmaf(w, va.z, az); aw = fmaf(w, va.w, aw);
            ssum += ev;
        }
#pragma unroll
        for (int m = 16; m < 64; m <<= 1) {
            ax += __shfl_xor(ax, m, 64); ay += __shfl_xor(ay, m, 64);
            az += __shfl_xor(az, m, 64); aw += __shfl_xor(aw, m, 64);
            ssum += __shfl_xor(ssum, m, 64);
        }
        const float rs = 1.0f / ssum;
        float ox = ax * rs, oy = ay * rs, oz = az * rs, ow = aw * rs;

        if (lsm_out) {
            float mx = fmaxf(fmaxf(ox, oy), fmaxf(oz, ow));
#pragma unroll
            for (int m = 1; m < 16; m <<= 1) mx = fmaxf(mx, __shfl_xor(mx, m, 64));
            float ex = __expf(ox - mx), ey = __expf(oy - mx);
            float ez = __expf(oz - mx), ew = __expf(ow - mx);
            float es = ex + ey + ez + ew;
#pragma unroll
            for (int m = 1; m < 16; m <<= 1) es += __shfl_xor(es, m, 64);
            float ls = __logf(es);
            if (sg == 0)
                *(float4*)(lsm_out + (size_t)d * HDIM + sl * 4) =
                    make_float4(ox - mx - ls, oy - mx - ls, oz - mx - ls, ow - mx - ls);
        } else {
            float ss = ox * ox + oy * oy + oz * oz + ow * ow;
#pragma unroll
            for (int m = 1; m < 16; m <<= 1) ss += __shfl_xor(ss, m, 64);
            float norm = sqrtf(ss);
            float rinv = 1.0f / fmaxf(norm, 1e-12f);
            if (sg == 0) {
                *(float4*)(hn_out + (size_t)d * HDIM + sl * 4) =
                    make_float4(ox * rinv, oy * rinv, oz * rinv, ow * rinv);
                if (sl == 0) nrm_out[d] = norm;
            }
        }
    }
}

extern "C" void kernel_launch(void* const* d_in, const int* in_sizes, int n_in,
                              void* d_out, int out_size, void* d_ws, size_t ws_size,
                              hipStream_t stream)
{
    const float* x     = (const float*)d_in[0];
    const int*   ei    = (const int*)d_in[1];   // [2, E] int32
    const float* W1    = (const float*)d_in[2];
    const float* b1    = (const float*)d_in[3];
    const float* beta2 = (const float*)d_in[4];
    float* out = (float*)d_out;

    const int N    = in_sizes[0] / FIN;
    const int E    = in_sizes[1] / 2;
    const int Etot = E + N;
    const int NB   = (N + B2 - 1) >> B2SHIFT;          // 49 coarse buckets
    const int nblk = (Etot + EB - 1) / EB;             // 208 edge blocks

    // ws layout (4B elems): hn1[N*64] hn2[N*64] nrm1[N] nrm2[N]
    //                       offsets[N+1] csr[Etot] ph[64*nblk] bbase[65]
    // pairs (u32, Etot) ALIASES hn2: dead before prop1 writes hn2.
    float* hn1     = (float*)d_ws;
    float* hn2     = hn1 + (size_t)N * HDIM;
    float* nrm1    = hn2 + (size_t)N * HDIM;
    float* nrm2    = nrm1 + N;
    int*   offsets = (int*)(nrm2 + N);
    int*   csr     = offsets + (N + 1);
    int*   ph      = csr + Etot;
    int*   bbase   = ph + 64 * nblk;
    unsigned* pairs = (unsigned*)hn2;

    const dim3 blk(256);

    // ---- CSR build (deterministic counting sort; no global data atomics) ----
    p1_hist<<<nblk, blk, 0, stream>>>(ei, ph, E, Etot, NB, nblk);
    p1_scan<<<1, blk, 0, stream>>>(ph, bbase, offsets, NB, nblk, N);
    p2_scatter<<<nblk, blk, 0, stream>>>(ei, ph, bbase, pairs, E, Etot, NB, nblk);
    p3_csr<<<NB, 1024, 0, stream>>>(pairs, bbase, offsets, csr, N);

    // ---- h = x@W1+b1 (MFMA), normalized ----
    const int ntiles = (N + 15) >> 4;
    gemm_mfma_k<<<(ntiles + 3) / 4, blk, 0, stream>>>(x, W1, b1, hn1, nrm1, N);

    // ---- prop 1 (beta = 1.0) ----
    prop_k<<<4096, blk, 0, stream>>>(hn1, nrm1, offsets, csr, nullptr,
                                     hn2, nrm2, nullptr, N);
    // ---- prop 2 (beta = beta2[0]) + fused log_softmax ----
    prop_k<<<4096, blk, 0, stream>>>(hn2, nrm2, offsets, csr, beta2,
                                     nullptr, nullptr, out, N);
}

// Round 5
// 352.374 us; speedup vs baseline: 4.4619x; 1.0280x over previous
//
#include <hip/hip_runtime.h>
#include <math.h>

#define FIN 128
#define HDIM 64

// CSR-build (counting sort) geometry. Assumes N <= 131072 (src fits 17 bits,
// coarse buckets <= 64). Problem instance: N=100000, E=1.6M.
#define EB 8192            // edges per block in p1/p2
#define B2SHIFT 11
#define B2 (1 << B2SHIFT)  // 2048 dst per coarse bucket
#define SRCBITS 17
#define SRCMASK ((1u << SRCBITS) - 1u)

typedef __attribute__((ext_vector_type(8))) short short8_t;  // 8 bf16 (4 VGPRs)
typedef __attribute__((ext_vector_type(4))) float f32x4;
typedef _Float16 h2_t __attribute__((ext_vector_type(2)));

__device__ __forceinline__ float2 h2f2(unsigned u) {
    h2_t h = __builtin_bit_cast(h2_t, u);
    return make_float2((float)h.x, (float)h.y);
}
__device__ __forceinline__ unsigned f2h2(float a, float b) {
    h2_t h; h.x = (_Float16)a; h.y = (_Float16)b;
    return __builtin_bit_cast(unsigned, h);
}
__device__ __forceinline__ unsigned short f2h1(float a) {
    _Float16 h = (_Float16)a;
    return __builtin_bit_cast(unsigned short, h);
}

__device__ __forceinline__ void split_bf16(float f, unsigned short& hi, unsigned short& lo) {
    unsigned b = __builtin_bit_cast(unsigned, f);
    hi = (unsigned short)(b >> 16);
    float fh = __builtin_bit_cast(float, b & 0xFFFF0000u);
    float fl = f - fh;
    lo = (unsigned short)(__builtin_bit_cast(unsigned, fl) >> 16);
}

// ---------------- CSR build: deterministic two-level counting sort ----------------

__global__ __launch_bounds__(256) void p1_hist(
    const int* __restrict__ ei, int* __restrict__ ph,
    int E, int Etot, int NB, int nblk)
{
    __shared__ int h[64];
    if (threadIdx.x < 64) h[threadIdx.x] = 0;
    __syncthreads();
    const int base = blockIdx.x * EB;
    const int end = min(base + EB, Etot);
    for (int e = base + (int)threadIdx.x; e < end; e += 256) {
        int d = (e < E) ? ei[E + e] : (e - E);
        atomicAdd(&h[d >> B2SHIFT], 1);
    }
    __syncthreads();
    if ((int)threadIdx.x < NB) ph[threadIdx.x * nblk + blockIdx.x] = h[threadIdx.x];
}

__global__ __launch_bounds__(256) void p1_scan(
    int* __restrict__ ph, int* __restrict__ bbase, int* __restrict__ offsets,
    int NB, int nblk, int N)
{
    __shared__ int btot[64];
    const int lane = threadIdx.x & 63, w = threadIdx.x >> 6;
    for (int b = w; b < NB; b += 4) {
        int carry = 0;
        for (int c = 0; c < nblk; c += 64) {
            int i = c + lane;
            int v = (i < nblk) ? ph[b * nblk + i] : 0;
            int s = v;
#pragma unroll
            for (int off = 1; off < 64; off <<= 1) {
                int u = __shfl_up(s, off, 64);
                if (lane >= off) s += u;
            }
            if (i < nblk) ph[b * nblk + i] = carry + s - v;
            carry += __shfl(s, 63, 64);
        }
        if (lane == 0) btot[b] = carry;
    }
    __syncthreads();
    if (w == 0) {
        int v = (lane < NB) ? btot[lane] : 0;
        int s = v;
#pragma unroll
        for (int off = 1; off < 64; off <<= 1) {
            int u = __shfl_up(s, off, 64);
            if (lane >= off) s += u;
        }
        if (lane < NB) bbase[lane] = s - v;
        if (lane == NB - 1) { bbase[NB] = s; offsets[N] = s; }
    }
}

__global__ __launch_bounds__(256) void p2_scatter(
    const int* __restrict__ ei, const int* __restrict__ ph,
    const int* __restrict__ bbase, unsigned* __restrict__ pairs,
    int E, int Etot, int NB, int nblk)
{
    __shared__ int cur[64];
    if ((int)threadIdx.x < NB)
        cur[threadIdx.x] = bbase[threadIdx.x] + ph[threadIdx.x * nblk + blockIdx.x];
    __syncthreads();
    const int base = blockIdx.x * EB;
    const int end = min(base + EB, Etot);
    for (int e = base + (int)threadIdx.x; e < end; e += 256) {
        int s, d;
        if (e < E) { s = ei[e]; d = ei[E + e]; }
        else       { s = e - E; d = s; }
        int pos = atomicAdd(&cur[d >> B2SHIFT], 1);
        pairs[pos] = ((unsigned)(d & (B2 - 1)) << SRCBITS) | (unsigned)s;
    }
}

__global__ __launch_bounds__(1024) void p3_csr(
    const unsigned* __restrict__ pairs, const int* __restrict__ bbase,
    int* __restrict__ offsets, int* __restrict__ csr, int N)
{
    __shared__ int hist[B2];
    __shared__ int wp[16];
    const int b = blockIdx.x;
    const int p0 = bbase[b], p1 = bbase[b + 1];
    const int dbase = b << B2SHIFT;
    const int lane = threadIdx.x & 63, w = threadIdx.x >> 6;
    hist[threadIdx.x] = 0; hist[threadIdx.x + 1024] = 0;
    __syncthreads();
    for (int i = p0 + (int)threadIdx.x; i < p1; i += 1024)
        atomicAdd(&hist[pairs[i] >> SRCBITS], 1);
    __syncthreads();
    const int v0 = hist[2 * threadIdx.x], v1 = hist[2 * threadIdx.x + 1];
    const int t = v0 + v1;
    int s = t;
#pragma unroll
    for (int off = 1; off < 64; off <<= 1) {
        int u = __shfl_up(s, off, 64);
        if (lane >= off) s += u;
    }
    if (lane == 63) wp[w] = s;
    __syncthreads();
    if (w == 0 && lane < 16) {
        int xx = wp[lane];
#pragma unroll
        for (int off = 1; off < 16; off <<= 1) {
            int u = __shfl_up(xx, off, 64);
            if (lane >= off) xx += u;
        }
        wp[lane] = xx;
    }
    __syncthreads();
    const int tex = ((w == 0) ? 0 : wp[w - 1]) + (s - t);
    const int e0 = tex, e1 = tex + v0;
    const int d0 = dbase + 2 * (int)threadIdx.x, d1 = d0 + 1;
    if (d0 < N) offsets[d0] = p0 + e0;
    if (d1 < N) offsets[d1] = p0 + e1;
    __syncthreads();
    hist[2 * threadIdx.x] = e0; hist[2 * threadIdx.x + 1] = e1;
    __syncthreads();
    for (int i = p0 + (int)threadIdx.x; i < p1; i += 1024) {
        unsigned pk = pairs[i];
        int pos = p0 + atomicAdd(&hist[pk >> SRCBITS], 1);
        csr[pos] = (int)(pk & SRCMASK);
    }
}

// ---------------- GEMM via MFMA (fp32 emulated with bf16 hi/lo split) ----------------
// Output hn is fp16 (normalized rows), nrm holds f32 L2 norms.
__global__ __launch_bounds__(256) void gemm_mfma_k(
    const float* __restrict__ x, const float* __restrict__ W,
    const float* __restrict__ b, unsigned short* __restrict__ hn,
    float* __restrict__ nrm, int n)
{
    __shared__ uint4 sB[2][4][4][64];   // [hi/lo][kc][nt][lane] = 32 KB
    for (int idx = threadIdx.x; idx < 2048; idx += 256) {
        int lanei = idx & 63;
        int f = idx >> 6;
        int nt = f & 3, kc = (f >> 2) & 3, hl = f >> 4;
        int col = nt * 16 + (lanei & 15);
        int kb  = kc * 32 + (lanei >> 4) * 8;
        unsigned u[4];
#pragma unroll
        for (int jj = 0; jj < 4; ++jj) {
            unsigned short h0, l0, h1, l1;
            split_bf16(W[(size_t)(kb + 2 * jj)     * HDIM + col], h0, l0);
            split_bf16(W[(size_t)(kb + 2 * jj + 1) * HDIM + col], h1, l1);
            u[jj] = hl ? ((unsigned)l0 | ((unsigned)l1 << 16))
                       : ((unsigned)h0 | ((unsigned)h1 << 16));
        }
        uint4 q; q.x = u[0]; q.y = u[1]; q.z = u[2]; q.w = u[3];
        sB[hl][kc][nt][lanei] = q;
    }
    __syncthreads();

    const int lane = threadIdx.x & 63;
    const int l15 = lane & 15, l4 = lane >> 4;
    const int gw = (int)((blockIdx.x * 256 + threadIdx.x) >> 6);
    const int nw = (int)((gridDim.x * 256) >> 6);
    const int ntiles = (n + 15) >> 4;

    const float bc0 = b[l15], bc1 = b[16 + l15], bc2 = b[32 + l15], bc3 = b[48 + l15];

    for (int tile = gw; tile < ntiles; tile += nw) {
        const int rowbase = tile << 4;
        int arow = rowbase + l15; if (arow >= n) arow = n - 1;
        const float* xp = x + (size_t)arow * FIN + l4 * 8;

        f32x4 acc0 = {bc0, bc0, bc0, bc0};
        f32x4 acc1 = {bc1, bc1, bc1, bc1};
        f32x4 acc2 = {bc2, bc2, bc2, bc2};
        f32x4 acc3 = {bc3, bc3, bc3, bc3};

#pragma unroll
        for (int kc = 0; kc < 4; ++kc) {
            float4 xa = *(const float4*)(xp + kc * 32);
            float4 xb = *(const float4*)(xp + kc * 32 + 4);
            float v[8] = {xa.x, xa.y, xa.z, xa.w, xb.x, xb.y, xb.z, xb.w};
            short8_t ah, al;
#pragma unroll
            for (int j = 0; j < 8; ++j) {
                unsigned bb = __builtin_bit_cast(unsigned, v[j]);
                ah[j] = (short)(bb >> 16);
                float fl = v[j] - __builtin_bit_cast(float, bb & 0xFFFF0000u);
                al[j] = (short)(__builtin_bit_cast(unsigned, fl) >> 16);
            }
#pragma unroll
            for (int nt = 0; nt < 4; ++nt) {
                short8_t bh = __builtin_bit_cast(short8_t, sB[0][kc][nt][lane]);
                short8_t bl = __builtin_bit_cast(short8_t, sB[1][kc][nt][lane]);
                f32x4* pacc = (nt == 0) ? &acc0 : (nt == 1) ? &acc1 : (nt == 2) ? &acc2 : &acc3;
                *pacc = __builtin_amdgcn_mfma_f32_16x16x32_bf16(ah, bh, *pacc, 0, 0, 0);
                *pacc = __builtin_amdgcn_mfma_f32_16x16x32_bf16(al, bh, *pacc, 0, 0, 0);
                *pacc = __builtin_amdgcn_mfma_f32_16x16x32_bf16(ah, bl, *pacc, 0, 0, 0);
            }
        }

        float ss0 = acc0.x*acc0.x + acc1.x*acc1.x + acc2.x*acc2.x + acc3.x*acc3.x;
        float ss1 = acc0.y*acc0.y + acc1.y*acc1.y + acc2.y*acc2.y + acc3.y*acc3.y;
        float ss2 = acc0.z*acc0.z + acc1.z*acc1.z + acc2.z*acc2.z + acc3.z*acc3.z;
        float ss3 = acc0.w*acc0.w + acc1.w*acc1.w + acc2.w*acc2.w + acc3.w*acc3.w;
#pragma unroll
        for (int m = 1; m < 16; m <<= 1) {
            ss0 += __shfl_xor(ss0, m, 64);
            ss1 += __shfl_xor(ss1, m, 64);
            ss2 += __shfl_xor(ss2, m, 64);
            ss3 += __shfl_xor(ss3, m, 64);
        }
        float n0 = sqrtf(ss0), n1 = sqrtf(ss1), n2 = sqrtf(ss2), n3 = sqrtf(ss3);
        float r0 = 1.0f / fmaxf(n0, 1e-12f), r1 = 1.0f / fmaxf(n1, 1e-12f);
        float r2 = 1.0f / fmaxf(n2, 1e-12f), r3 = 1.0f / fmaxf(n3, 1e-12f);
        const int rowb = rowbase + l4 * 4;
        if (l15 == 0) {
            if (rowb + 0 < n) nrm[rowb + 0] = n0;
            if (rowb + 1 < n) nrm[rowb + 1] = n1;
            if (rowb + 2 < n) nrm[rowb + 2] = n2;
            if (rowb + 3 < n) nrm[rowb + 3] = n3;
        }
#pragma unroll
        for (int nt = 0; nt < 4; ++nt) {
            f32x4 a = (nt == 0) ? acc0 : (nt == 1) ? acc1 : (nt == 2) ? acc2 : acc3;
            const int col = nt * 16 + l15;
            if (rowb + 0 < n) hn[(size_t)(rowb + 0) * HDIM + col] = f2h1(a.x * r0);
            if (rowb + 1 < n) hn[(size_t)(rowb + 1) * HDIM + col] = f2h1(a.y * r1);
            if (rowb + 2 < n) hn[(size_t)(rowb + 2) * HDIM + col] = f2h1(a.z * r2);
            if (rowb + 3 < n) hn[(size_t)(rowb + 3) * HDIM + col] = f2h1(a.w * r3);
        }
    }
}

// ---------------- AGNN propagation: fp16 rows, wave per dst, 4 edges/iter ----------------
__global__ __launch_bounds__(256) void prop_k(
    const unsigned short* __restrict__ hn, const float* __restrict__ nrm,
    const int* __restrict__ offsets, const int* __restrict__ csr,
    const float* __restrict__ beta_ptr,
    unsigned short* __restrict__ hn_out, float* __restrict__ nrm_out,
    float* __restrict__ lsm_out, int n)
{
    const int lane = threadIdx.x & 63;
    const int sg = lane >> 4;        // subgroup 0..3, one edge each
    const int sl = lane & 15;        // 4 halves per lane (uint2)
    const int gw = (int)((blockIdx.x * 256 + threadIdx.x) >> 6);
    const int nw = (int)((gridDim.x * 256) >> 6);
    const float beta = beta_ptr ? beta_ptr[0] : 1.0f;
    const float shift = fabsf(beta);

    for (int d = gw; d < n; d += nw) {
        const uint2 hdu = *(const uint2*)(hn + ((size_t)d << 6) + (sl << 2));
        const float2 hd0 = h2f2(hdu.x), hd1 = h2f2(hdu.y);
        const int i0 = offsets[d], i1 = offsets[d + 1];
        const int iters = (i1 - i0 + 3) >> 2;
        float ax = 0.f, ay = 0.f, az = 0.f, aw = 0.f, ssum = 0.f;
        for (int t = 0; t < iters; ++t) {
            const int e = i0 + t * 4 + sg;
            const bool valid = e < i1;
            const int s = valid ? csr[e] : d;
            const uint2 vu = *(const uint2*)(hn + ((size_t)s << 6) + (sl << 2));
            const float na = nrm[s];
            const float2 v0 = h2f2(vu.x), v1 = h2f2(vu.y);
            float p = v0.x * hd0.x + v0.y * hd0.y + v1.x * hd1.x + v1.y * hd1.y;
            p += __shfl_xor(p, 1, 64);
            p += __shfl_xor(p, 2, 64);
            p += __shfl_xor(p, 4, 64);
            p += __shfl_xor(p, 8, 64);
            const float ev = valid ? __expf(beta * p - shift) : 0.f;
            const float w = ev * na;
            ax = fmaf(w, v0.x, ax); ay = fmaf(w, v0.y, ay);
            az = fmaf(w, v1.x, az); aw = fmaf(w, v1.y, aw);
            ssum += ev;
        }
#pragma unroll
        for (int m = 16; m < 64; m <<= 1) {
            ax += __shfl_xor(ax, m, 64); ay += __shfl_xor(ay, m, 64);
            az += __shfl_xor(az, m, 64); aw += __shfl_xor(aw, m, 64);
            ssum += __shfl_xor(ssum, m, 64);
        }
        const float rs = 1.0f / ssum;          // self loop => ssum > 0
        float ox = ax * rs, oy = ay * rs, oz = az * rs, ow = aw * rs;

        if (lsm_out) {
            float mx = fmaxf(fmaxf(ox, oy), fmaxf(oz, ow));
#pragma unroll
            for (int m = 1; m < 16; m <<= 1) mx = fmaxf(mx, __shfl_xor(mx, m, 64));
            float ex = __expf(ox - mx), ey = __expf(oy - mx);
            float ez = __expf(oz - mx), ew = __expf(ow - mx);
            float es = ex + ey + ez + ew;
#pragma unroll
            for (int m = 1; m < 16; m <<= 1) es += __shfl_xor(es, m, 64);
            float ls = __logf(es);
            if (sg == 0)
                *(float4*)(lsm_out + ((size_t)d << 6) + (sl << 2)) =
                    make_float4(ox - mx - ls, oy - mx - ls, oz - mx - ls, ow - mx - ls);
        } else {
            float ss = ox * ox + oy * oy + oz * oz + ow * ow;
#pragma unroll
            for (int m = 1; m < 16; m <<= 1) ss += __shfl_xor(ss, m, 64);
            float norm = sqrtf(ss);
            float rinv = 1.0f / fmaxf(norm, 1e-12f);
            if (sg == 0) {
                *(uint2*)(hn_out + ((size_t)d << 6) + (sl << 2)) =
                    make_uint2(f2h2(ox * rinv, oy * rinv), f2h2(oz * rinv, ow * rinv));
                if (sl == 0) nrm_out[d] = norm;
            }
        }
    }
}

extern "C" void kernel_launch(void* const* d_in, const int* in_sizes, int n_in,
                              void* d_out, int out_size, void* d_ws, size_t ws_size,
                              hipStream_t stream)
{
    const float* x     = (const float*)d_in[0];
    const int*   ei    = (const int*)d_in[1];   // [2, E] int32
    const float* W1    = (const float*)d_in[2];
    const float* b1    = (const float*)d_in[3];
    const float* beta2 = (const float*)d_in[4];
    float* out = (float*)d_out;

    const int N    = in_sizes[0] / FIN;
    const int E    = in_sizes[1] / 2;
    const int Etot = E + N;
    const int NB   = (N + B2 - 1) >> B2SHIFT;          // 49 coarse buckets
    const int nblk = (Etot + EB - 1) / EB;             // 208 edge blocks

    // ws layout: hn1h[N*64 u16] hn2h[N*64 u16] nrm1[N f32] nrm2[N f32]
    //            offsets[N+1] csr[Etot] ph[64*nblk] bbase[65]
    // pairs (u32, Etot = 6.8 MB) ALIASES hn2h (12.8 MB): dead before prop1 writes.
    unsigned short* hn1h = (unsigned short*)d_ws;
    unsigned short* hn2h = hn1h + (size_t)N * HDIM;
    float* nrm1    = (float*)(hn2h + (size_t)N * HDIM);
    float* nrm2    = nrm1 + N;
    int*   offsets = (int*)(nrm2 + N);
    int*   csr     = offsets + (N + 1);
    int*   ph      = csr + Etot;
    int*   bbase   = ph + 64 * nblk;
    unsigned* pairs = (unsigned*)hn2h;

    const dim3 blk(256);

    // ---- CSR build (deterministic counting sort; no global data atomics) ----
    p1_hist<<<nblk, blk, 0, stream>>>(ei, ph, E, Etot, NB, nblk);
    p1_scan<<<1, blk, 0, stream>>>(ph, bbase, offsets, NB, nblk, N);
    p2_scatter<<<nblk, blk, 0, stream>>>(ei, ph, bbase, pairs, E, Etot, NB, nblk);
    p3_csr<<<NB, 1024, 0, stream>>>(pairs, bbase, offsets, csr, N);

    // ---- h = x@W1+b1 (MFMA), normalized, fp16 ----
    const int ntiles = (N + 15) >> 4;
    gemm_mfma_k<<<(ntiles + 3) / 4, blk, 0, stream>>>(x, W1, b1, hn1h, nrm1, N);

    // ---- prop 1 (beta = 1.0) ----
    prop_k<<<4096, blk, 0, stream>>>(hn1h, nrm1, offsets, csr, nullptr,
                                     hn2h, nrm2, nullptr, N);
    // ---- prop 2 (beta = beta2[0]) + fused log_softmax ----
    prop_k<<<4096, blk, 0, stream>>>(hn2h, nrm2, offsets, csr, beta2,
                                     nullptr, nullptr, out, N);
}

// Round 6
// 249.344 us; speedup vs baseline: 6.3056x; 1.4132x over previous
//
#include <hip/hip_runtime.h>
#include <math.h>

#define FIN 128
#define HDIM 64

// CSR-build (counting sort) geometry. Assumes N <= 131072 (src fits 17 bits,
// coarse buckets <= 256), Etot <= 2.09M (nblk <= 256). Instance: N=100k, E=1.6M.
#define EB 8192            // edges per block in p1/p2
#define B2SHIFT 9
#define B2 (1 << B2SHIFT)  // 512 dst per coarse bucket
#define SRCBITS 17
#define SRCMASK ((1u << SRCBITS) - 1u)

typedef __attribute__((ext_vector_type(8))) short short8_t;  // 8 bf16 (4 VGPRs)
typedef __attribute__((ext_vector_type(4))) float f32x4;
typedef _Float16 h2_t __attribute__((ext_vector_type(2)));

__device__ __forceinline__ float2 h2f2(unsigned u) {
    h2_t h = __builtin_bit_cast(h2_t, u);
    return make_float2((float)h.x, (float)h.y);
}
__device__ __forceinline__ unsigned f2h2(float a, float b) {
    h2_t h; h.x = (_Float16)a; h.y = (_Float16)b;
    return __builtin_bit_cast(unsigned, h);
}
__device__ __forceinline__ unsigned short f2h1(float a) {
    _Float16 h = (_Float16)a;
    return __builtin_bit_cast(unsigned short, h);
}

__device__ __forceinline__ void split_bf16(float f, unsigned short& hi, unsigned short& lo) {
    unsigned b = __builtin_bit_cast(unsigned, f);
    hi = (unsigned short)(b >> 16);
    float fh = __builtin_bit_cast(float, b & 0xFFFF0000u);
    float fl = f - fh;
    lo = (unsigned short)(__builtin_bit_cast(unsigned, fl) >> 16);
}

// 8-wide dot of packed fp16 against f32-promoted: compiler emits v_fma_mix_f32.
__device__ __forceinline__ float dot8(uint4 v, const float* hd) {
    float2 a = h2f2(v.x), b = h2f2(v.y), c = h2f2(v.z), d = h2f2(v.w);
    float p = a.x * hd[0];
    p = fmaf(a.y, hd[1], p);
    p = fmaf(b.x, hd[2], p);
    p = fmaf(b.y, hd[3], p);
    p = fmaf(c.x, hd[4], p);
    p = fmaf(c.y, hd[5], p);
    p = fmaf(d.x, hd[6], p);
    p = fmaf(d.y, hd[7], p);
    return p;
}
__device__ __forceinline__ void acc8(float w, uint4 v, float* a) {
    float2 f0 = h2f2(v.x), f1 = h2f2(v.y), f2 = h2f2(v.z), f3 = h2f2(v.w);
    a[0] = fmaf(w, f0.x, a[0]); a[1] = fmaf(w, f0.y, a[1]);
    a[2] = fmaf(w, f1.x, a[2]); a[3] = fmaf(w, f1.y, a[3]);
    a[4] = fmaf(w, f2.x, a[4]); a[5] = fmaf(w, f2.y, a[5]);
    a[6] = fmaf(w, f3.x, a[6]); a[7] = fmaf(w, f3.y, a[7]);
}

// ---------------- CSR build: deterministic two-level counting sort ----------------

__global__ __launch_bounds__(256) void p1_hist(
    const int* __restrict__ ei, int* __restrict__ ph,
    int E, int Etot, int NB, int nblk)
{
    __shared__ int h[256];
    h[threadIdx.x] = 0;
    __syncthreads();
    const int base = blockIdx.x * EB;
    const int end = min(base + EB, Etot);
    for (int e = base + (int)threadIdx.x; e < end; e += 256) {
        int d = (e < E) ? ei[E + e] : (e - E);
        atomicAdd(&h[d >> B2SHIFT], 1);
    }
    __syncthreads();
    if ((int)threadIdx.x < NB) ph[threadIdx.x * nblk + blockIdx.x] = h[threadIdx.x];
}

// One block per bucket: exclusive scan of ph[b][0..nblk) in place, total -> btot[b]
__global__ __launch_bounds__(256) void p1_scanA(
    int* __restrict__ ph, int* __restrict__ btot, int nblk)
{
    __shared__ int wpart[4];
    const int b = blockIdx.x;
    const int t = threadIdx.x, lane = t & 63, w = t >> 6;
    int v = (t < nblk) ? ph[b * nblk + t] : 0;
    int s = v;
#pragma unroll
    for (int off = 1; off < 64; off <<= 1) {
        int u = __shfl_up(s, off, 64);
        if (lane >= off) s += u;
    }
    if (lane == 63) wpart[w] = s;
    __syncthreads();
    int wex = 0;
#pragma unroll
    for (int i = 0; i < 3; ++i) if (i < w) wex += wpart[i];
    if (t < nblk) ph[b * nblk + t] = wex + s - v;
    if (t == 255) btot[b] = wex + s;
}

// Single tiny block: scan bucket totals -> bbase[NB+1]; offsets[N] = Etot.
__global__ __launch_bounds__(256) void p1_scanB(
    const int* __restrict__ btot, int* __restrict__ bbase,
    int* __restrict__ offsets, int NB, int N)
{
    __shared__ int wpart[4];
    const int t = threadIdx.x, lane = t & 63, w = t >> 6;
    int v = (t < NB) ? btot[t] : 0;
    int s = v;
#pragma unroll
    for (int off = 1; off < 64; off <<= 1) {
        int u = __shfl_up(s, off, 64);
        if (lane >= off) s += u;
    }
    if (lane == 63) wpart[w] = s;
    __syncthreads();
    int wex = 0;
#pragma unroll
    for (int i = 0; i < 3; ++i) if (i < w) wex += wpart[i];
    if (t < NB) bbase[t] = wex + s - v;
    if (t == 255) { bbase[NB] = wex + s; offsets[N] = wex + s; }
}

__global__ __launch_bounds__(256) void p2_scatter(
    const int* __restrict__ ei, const int* __restrict__ ph,
    const int* __restrict__ bbase, unsigned* __restrict__ pairs,
    int E, int Etot, int NB, int nblk)
{
    __shared__ int cur[256];
    if ((int)threadIdx.x < NB)
        cur[threadIdx.x] = bbase[threadIdx.x] + ph[threadIdx.x * nblk + blockIdx.x];
    __syncthreads();
    const int base = blockIdx.x * EB;
    const int end = min(base + EB, Etot);
    for (int e = base + (int)threadIdx.x; e < end; e += 256) {
        int s, d;
        if (e < E) { s = ei[e]; d = ei[E + e]; }
        else       { s = e - E; d = s; }
        int pos = atomicAdd(&cur[d >> B2SHIFT], 1);
        pairs[pos] = ((unsigned)(d & (B2 - 1)) << SRCBITS) | (unsigned)s;
    }
}

// One block (256 thr) per bucket: 512-bin LDS hist + scan -> offsets, then scatter.
__global__ __launch_bounds__(256) void p3_csr(
    const unsigned* __restrict__ pairs, const int* __restrict__ bbase,
    int* __restrict__ offsets, int* __restrict__ csr, int N)
{
    __shared__ int hist[B2];
    __shared__ int wp[4];
    const int b = blockIdx.x;
    const int p0 = bbase[b], p1 = bbase[b + 1];
    const int dbase = b << B2SHIFT;
    const int lane = threadIdx.x & 63, w = threadIdx.x >> 6;
    hist[threadIdx.x] = 0; hist[threadIdx.x + 256] = 0;
    __syncthreads();
    for (int i = p0 + (int)threadIdx.x; i < p1; i += 256)
        atomicAdd(&hist[pairs[i] >> SRCBITS], 1);
    __syncthreads();
    const int v0 = hist[2 * threadIdx.x], v1 = hist[2 * threadIdx.x + 1];
    const int t = v0 + v1;
    int s = t;
#pragma unroll
    for (int off = 1; off < 64; off <<= 1) {
        int u = __shfl_up(s, off, 64);
        if (lane >= off) s += u;
    }
    if (lane == 63) wp[w] = s;
    __syncthreads();
    int wex = 0;
#pragma unroll
    for (int i = 0; i < 3; ++i) if (i < w) wex += wp[i];
    const int tex = wex + (s - t);
    const int e0 = tex, e1 = tex + v0;
    const int d0 = dbase + 2 * (int)threadIdx.x, d1 = d0 + 1;
    if (d0 < N) offsets[d0] = p0 + e0;
    if (d1 < N) offsets[d1] = p0 + e1;
    __syncthreads();
    hist[2 * threadIdx.x] = e0; hist[2 * threadIdx.x + 1] = e1;
    __syncthreads();
    for (int i = p0 + (int)threadIdx.x; i < p1; i += 256) {
        unsigned pk = pairs[i];
        int pos = p0 + atomicAdd(&hist[pk >> SRCBITS], 1);
        csr[pos] = (int)(pk & SRCMASK);
    }
}

// ---------------- GEMM via MFMA (fp32 emulated with bf16 hi/lo split) ----------------
// Output hn is fp16 (normalized rows), nrm holds f32 L2 norms.
__global__ __launch_bounds__(256) void gemm_mfma_k(
    const float* __restrict__ x, const float* __restrict__ W,
    const float* __restrict__ b, unsigned short* __restrict__ hn,
    float* __restrict__ nrm, int n)
{
    __shared__ uint4 sB[2][4][4][64];   // [hi/lo][kc][nt][lane] = 32 KB
    for (int idx = threadIdx.x; idx < 2048; idx += 256) {
        int lanei = idx & 63;
        int f = idx >> 6;
        int nt = f & 3, kc = (f >> 2) & 3, hl = f >> 4;
        int col = nt * 16 + (lanei & 15);
        int kb  = kc * 32 + (lanei >> 4) * 8;
        unsigned u[4];
#pragma unroll
        for (int jj = 0; jj < 4; ++jj) {
            unsigned short h0, l0, h1, l1;
            split_bf16(W[(size_t)(kb + 2 * jj)     * HDIM + col], h0, l0);
            split_bf16(W[(size_t)(kb + 2 * jj + 1) * HDIM + col], h1, l1);
            u[jj] = hl ? ((unsigned)l0 | ((unsigned)l1 << 16))
                       : ((unsigned)h0 | ((unsigned)h1 << 16));
        }
        uint4 q; q.x = u[0]; q.y = u[1]; q.z = u[2]; q.w = u[3];
        sB[hl][kc][nt][lanei] = q;
    }
    __syncthreads();

    const int lane = threadIdx.x & 63;
    const int l15 = lane & 15, l4 = lane >> 4;
    const int gw = (int)((blockIdx.x * 256 + threadIdx.x) >> 6);
    const int nw = (int)((gridDim.x * 256) >> 6);
    const int ntiles = (n + 15) >> 4;

    const float bc0 = b[l15], bc1 = b[16 + l15], bc2 = b[32 + l15], bc3 = b[48 + l15];

    for (int tile = gw; tile < ntiles; tile += nw) {
        const int rowbase = tile << 4;
        int arow = rowbase + l15; if (arow >= n) arow = n - 1;
        const float* xp = x + (size_t)arow * FIN + l4 * 8;

        f32x4 acc0 = {bc0, bc0, bc0, bc0};
        f32x4 acc1 = {bc1, bc1, bc1, bc1};
        f32x4 acc2 = {bc2, bc2, bc2, bc2};
        f32x4 acc3 = {bc3, bc3, bc3, bc3};

#pragma unroll
        for (int kc = 0; kc < 4; ++kc) {
            float4 xa = *(const float4*)(xp + kc * 32);
            float4 xb = *(const float4*)(xp + kc * 32 + 4);
            float v[8] = {xa.x, xa.y, xa.z, xa.w, xb.x, xb.y, xb.z, xb.w};
            short8_t ah, al;
#pragma unroll
            for (int j = 0; j < 8; ++j) {
                unsigned bb = __builtin_bit_cast(unsigned, v[j]);
                ah[j] = (short)(bb >> 16);
                float fl = v[j] - __builtin_bit_cast(float, bb & 0xFFFF0000u);
                al[j] = (short)(__builtin_bit_cast(unsigned, fl) >> 16);
            }
#pragma unroll
            for (int nt = 0; nt < 4; ++nt) {
                short8_t bh = __builtin_bit_cast(short8_t, sB[0][kc][nt][lane]);
                short8_t bl = __builtin_bit_cast(short8_t, sB[1][kc][nt][lane]);
                f32x4* pacc = (nt == 0) ? &acc0 : (nt == 1) ? &acc1 : (nt == 2) ? &acc2 : &acc3;
                *pacc = __builtin_amdgcn_mfma_f32_16x16x32_bf16(ah, bh, *pacc, 0, 0, 0);
                *pacc = __builtin_amdgcn_mfma_f32_16x16x32_bf16(al, bh, *pacc, 0, 0, 0);
                *pacc = __builtin_amdgcn_mfma_f32_16x16x32_bf16(ah, bl, *pacc, 0, 0, 0);
            }
        }

        float ss0 = acc0.x*acc0.x + acc1.x*acc1.x + acc2.x*acc2.x + acc3.x*acc3.x;
        float ss1 = acc0.y*acc0.y + acc1.y*acc1.y + acc2.y*acc2.y + acc3.y*acc3.y;
        float ss2 = acc0.z*acc0.z + acc1.z*acc1.z + acc2.z*acc2.z + acc3.z*acc3.z;
        float ss3 = acc0.w*acc0.w + acc1.w*acc1.w + acc2.w*acc2.w + acc3.w*acc3.w;
#pragma unroll
        for (int m = 1; m < 16; m <<= 1) {
            ss0 += __shfl_xor(ss0, m, 64);
            ss1 += __shfl_xor(ss1, m, 64);
            ss2 += __shfl_xor(ss2, m, 64);
            ss3 += __shfl_xor(ss3, m, 64);
        }
        float n0 = sqrtf(ss0), n1 = sqrtf(ss1), n2 = sqrtf(ss2), n3 = sqrtf(ss3);
        float r0 = 1.0f / fmaxf(n0, 1e-12f), r1 = 1.0f / fmaxf(n1, 1e-12f);
        float r2 = 1.0f / fmaxf(n2, 1e-12f), r3 = 1.0f / fmaxf(n3, 1e-12f);
        const int rowb = rowbase + l4 * 4;
        if (l15 == 0) {
            if (rowb + 0 < n) nrm[rowb + 0] = n0;
            if (rowb + 1 < n) nrm[rowb + 1] = n1;
            if (rowb + 2 < n) nrm[rowb + 2] = n2;
            if (rowb + 3 < n) nrm[rowb + 3] = n3;
        }
#pragma unroll
        for (int nt = 0; nt < 4; ++nt) {
            f32x4 a = (nt == 0) ? acc0 : (nt == 1) ? acc1 : (nt == 2) ? acc2 : acc3;
            const int col = nt * 16 + l15;
            if (rowb + 0 < n) hn[(size_t)(rowb + 0) * HDIM + col] = f2h1(a.x * r0);
            if (rowb + 1 < n) hn[(size_t)(rowb + 1) * HDIM + col] = f2h1(a.y * r1);
            if (rowb + 2 < n) hn[(size_t)(rowb + 2) * HDIM + col] = f2h1(a.z * r2);
            if (rowb + 3 < n) hn[(size_t)(rowb + 3) * HDIM + col] = f2h1(a.w * r3);
        }
    }
}

// ---------------- AGNN propagation v2: 8-lane subgroup OWNS one dst ----------------
// Wave = 8 subgroups x 8 lanes; lane holds 8 halves (uint4) = cols [8*sl, 8*sl+8).
// Per edge: 1 coalesced 128B row gather, 8 mix-fma dot, 3-round 8-lane reduce,
// exp, 8 mix-fma accum. ssum/acc identical across subgroup lanes -> no epilogue
// cross-subgroup reduce. 2-edge unroll for memory-level parallelism.
__global__ __launch_bounds__(256) void prop_k(
    const unsigned short* __restrict__ hn, const float* __restrict__ nrm,
    const int* __restrict__ offsets, const int* __restrict__ csr,
    const float* __restrict__ beta_ptr,
    unsigned short* __restrict__ hn_out, float* __restrict__ nrm_out,
    float* __restrict__ lsm_out, int n)
{
    const int lane = threadIdx.x & 63;
    const int sl = lane & 7;
    const int wid = (int)((blockIdx.x * 256 + threadIdx.x) >> 6);
    int d = wid * 8 + (lane >> 3);
    const bool dvalid = d < n;
    if (!dvalid) d = n - 1;
    const float beta = beta_ptr ? beta_ptr[0] : 1.0f;
    const float shift = fabsf(beta);

    const uint4 hdu = *(const uint4*)(hn + ((size_t)d << 6) + (sl << 3));
    float hd[8];
    { float2 f0 = h2f2(hdu.x), f1 = h2f2(hdu.y), f2 = h2f2(hdu.z), f3 = h2f2(hdu.w);
      hd[0]=f0.x; hd[1]=f0.y; hd[2]=f1.x; hd[3]=f1.y;
      hd[4]=f2.x; hd[5]=f2.y; hd[6]=f3.x; hd[7]=f3.y; }

    const int i0 = offsets[d], i1 = offsets[d + 1];
    float acc[8] = {0,0,0,0,0,0,0,0};
    float ssum = 0.f;

    int e = i0;
    for (; e + 1 < i1; e += 2) {
        const int s0 = csr[e], s1 = csr[e + 1];
        const uint4 va = *(const uint4*)(hn + ((size_t)s0 << 6) + (sl << 3));
        const uint4 vb = *(const uint4*)(hn + ((size_t)s1 << 6) + (sl << 3));
        const float na = nrm[s0], nb = nrm[s1];
        float p0 = dot8(va, hd);
        float p1 = dot8(vb, hd);
        p0 += __shfl_xor(p0, 1, 64); p1 += __shfl_xor(p1, 1, 64);
        p0 += __shfl_xor(p0, 2, 64); p1 += __shfl_xor(p1, 2, 64);
        p0 += __shfl_xor(p0, 4, 64); p1 += __shfl_xor(p1, 4, 64);
        const float ev0 = __expf(beta * p0 - shift);
        const float ev1 = __expf(beta * p1 - shift);
        acc8(ev0 * na, va, acc);
        acc8(ev1 * nb, vb, acc);
        ssum += ev0 + ev1;
    }
    if (e < i1) {
        const int s0 = csr[e];
        const uint4 va = *(const uint4*)(hn + ((size_t)s0 << 6) + (sl << 3));
        const float na = nrm[s0];
        float p0 = dot8(va, hd);
        p0 += __shfl_xor(p0, 1, 64);
        p0 += __shfl_xor(p0, 2, 64);
        p0 += __shfl_xor(p0, 4, 64);
        const float ev0 = __expf(beta * p0 - shift);
        acc8(ev0 * na, va, acc);
        ssum += ev0;
    }

    const float rs = 1.0f / ssum;      // self loop => ssum > 0
    float o[8];
#pragma unroll
    for (int j = 0; j < 8; ++j) o[j] = acc[j] * rs;

    if (lsm_out) {
        float mx = o[0];
#pragma unroll
        for (int j = 1; j < 8; ++j) mx = fmaxf(mx, o[j]);
        mx = fmaxf(mx, __shfl_xor(mx, 1, 64));
        mx = fmaxf(mx, __shfl_xor(mx, 2, 64));
        mx = fmaxf(mx, __shfl_xor(mx, 4, 64));
        float es = 0.f;
#pragma unroll
        for (int j = 0; j < 8; ++j) es += __expf(o[j] - mx);
        es += __shfl_xor(es, 1, 64);
        es += __shfl_xor(es, 2, 64);
        es += __shfl_xor(es, 4, 64);
        const float ls = mx + __logf(es);
        if (dvalid) {
            float* op = lsm_out + ((size_t)d << 6) + (sl << 3);
            *(float4*)(op)     = make_float4(o[0]-ls, o[1]-ls, o[2]-ls, o[3]-ls);
            *(float4*)(op + 4) = make_float4(o[4]-ls, o[5]-ls, o[6]-ls, o[7]-ls);
        }
    } else {
        float ss = 0.f;
#pragma unroll
        for (int j = 0; j < 8; ++j) ss = fmaf(o[j], o[j], ss);
        ss += __shfl_xor(ss, 1, 64);
        ss += __shfl_xor(ss, 2, 64);
        ss += __shfl_xor(ss, 4, 64);
        const float norm = sqrtf(ss);
        const float rinv = 1.0f / fmaxf(norm, 1e-12f);
        if (dvalid) {
            uint4 q;
            q.x = f2h2(o[0] * rinv, o[1] * rinv);
            q.y = f2h2(o[2] * rinv, o[3] * rinv);
            q.z = f2h2(o[4] * rinv, o[5] * rinv);
            q.w = f2h2(o[6] * rinv, o[7] * rinv);
            *(uint4*)(hn_out + ((size_t)d << 6) + (sl << 3)) = q;
            if (sl == 0) nrm_out[d] = norm;
        }
    }
}

extern "C" void kernel_launch(void* const* d_in, const int* in_sizes, int n_in,
                              void* d_out, int out_size, void* d_ws, size_t ws_size,
                              hipStream_t stream)
{
    const float* x     = (const float*)d_in[0];
    const int*   ei    = (const int*)d_in[1];   // [2, E] int32
    const float* W1    = (const float*)d_in[2];
    const float* b1    = (const float*)d_in[3];
    const float* beta2 = (const float*)d_in[4];
    float* out = (float*)d_out;

    const int N    = in_sizes[0] / FIN;
    const int E    = in_sizes[1] / 2;
    const int Etot = E + N;
    const int NB   = (N + B2 - 1) >> B2SHIFT;          // 196 coarse buckets
    const int nblk = (Etot + EB - 1) / EB;             // 208 edge blocks

    // ws layout: hn1h[N*64 u16] hn2h[N*64 u16] nrm1[N f32] nrm2[N f32]
    //            offsets[N+1] csr[Etot] ph[256*nblk] bbase[257] btot[256]
    // pairs (u32, Etot = 6.8 MB) ALIASES hn2h (12.8 MB): dead before prop1 writes.
    unsigned short* hn1h = (unsigned short*)d_ws;
    unsigned short* hn2h = hn1h + (size_t)N * HDIM;
    float* nrm1    = (float*)(hn2h + (size_t)N * HDIM);
    float* nrm2    = nrm1 + N;
    int*   offsets = (int*)(nrm2 + N);
    int*   csr     = offsets + (N + 1);
    int*   ph      = csr + Etot;
    int*   bbase   = ph + 256 * nblk;
    int*   btot    = bbase + 257;
    unsigned* pairs = (unsigned*)hn2h;

    const dim3 blk(256);

    // ---- CSR build (deterministic counting sort; no global data atomics) ----
    p1_hist<<<nblk, blk, 0, stream>>>(ei, ph, E, Etot, NB, nblk);
    p1_scanA<<<NB, blk, 0, stream>>>(ph, btot, nblk);
    p1_scanB<<<1, blk, 0, stream>>>(btot, bbase, offsets, NB, N);
    p2_scatter<<<nblk, blk, 0, stream>>>(ei, ph, bbase, pairs, E, Etot, NB, nblk);
    p3_csr<<<NB, blk, 0, stream>>>(pairs, bbase, offsets, csr, N);

    // ---- h = x@W1+b1 (MFMA), normalized, fp16 ----
    const int ntiles = (N + 15) >> 4;
    gemm_mfma_k<<<(ntiles + 3) / 4, blk, 0, stream>>>(x, W1, b1, hn1h, nrm1, N);

    // ---- props: 8 dsts per wave, 32 per block ----
    const int pblocks = (N + 31) / 32;
    prop_k<<<pblocks, blk, 0, stream>>>(hn1h, nrm1, offsets, csr, nullptr,
                                        hn2h, nrm2, nullptr, N);
    prop_k<<<pblocks, blk, 0, stream>>>(hn2h, nrm2, offsets, csr, beta2,
                                        nullptr, nullptr, out, N);
}